// Round 10
// baseline (101.864 us; speedup 1.0000x reference)
//
#include <hip/hip_runtime.h>
#include <hip/hip_bf16.h>

// DeformableAttention: BS=4, Hq=Wq=64, C=256, M=8, K=4, L=4, CV=32
// SCALES = 64,32,16,8
//
// All-f16 pipeline with pre-transposed f16 weights:
//  D0 transpose_w: Wz,Wo,Wa,Wp,Wm (f32 [k][n]) -> f16 [n][k] in ws
//  D1 gemm_z_wp : z = f16(q@Wz+bz)  AND  wp_l = f16(feat_l@Wp+bp)
//  D2 gemm_zo_za: zo = f16(z@Wo+bo) AND za = f16(z@Wa+ba)   (pure GEMM)
//  D3 softmax3  : za -> attn f16 [b][p][m][16]  (register-local, no shfl)
//  D4 sample7   : cluster-cooperative coalesced tap loads (1 segment/instr)
//  D5 gemm_final: out = out_pre@Wm+bm -> f32
//
// ws (MB): z/out_pre@0(8) zo@16(8) attn@24(4)
//   wp0@28(8) wp1@36(2) wp2@38(.5) wp3@38.5(.125)
//   Wzt@40 Woat@40.25(384x256) Wpt@40.75 Wmt@41 za@42(4). Peak ~46 MB.

typedef __attribute__((ext_vector_type(8))) _Float16 half8;
typedef __attribute__((ext_vector_type(2))) _Float16 half2t;
typedef __attribute__((ext_vector_type(4))) float f32x4;

constexpr int LDT = 40;  // LDS row stride (f16 elems) = 80B

#if __has_builtin(__builtin_amdgcn_fdot2)
__device__ __forceinline__ float fdot2f(half2t a, half2t b, float c) {
    return __builtin_amdgcn_fdot2(a, b, c, false);
}
#else
__device__ __forceinline__ float fdot2f(half2t a, half2t b, float c) {
    return c + (float)a.x * (float)b.x + (float)a.y * (float)b.y;
}
#endif

// ---------------------------------------------------------------------------
// D0: transpose+convert weights. 64x64 tiles via LDS. 72 blocks.
// ---------------------------------------------------------------------------
__global__ __launch_bounds__(256) void transpose_w(
    const float* __restrict__ Wz, const float* __restrict__ Wo,
    const float* __restrict__ Wa, const float* __restrict__ Wp,
    const float* __restrict__ Wm,
    _Float16* __restrict__ Wzt, _Float16* __restrict__ Woat,
    _Float16* __restrict__ Wpt, _Float16* __restrict__ Wmt)
{
    __shared__ float ts[64][65];
    const int bid = blockIdx.x;
    const float* src; _Float16* dst; int N, tile;
    if      (bid < 16) { src = Wz; dst = Wzt;          N = 256; tile = bid; }
    else if (bid < 32) { src = Wo; dst = Woat;         N = 256; tile = bid - 16; }
    else if (bid < 40) { src = Wa; dst = Woat + 65536; N = 128; tile = bid - 32; }
    else if (bid < 56) { src = Wp; dst = Wpt;          N = 256; tile = bid - 40; }
    else               { src = Wm; dst = Wmt;          N = 256; tile = bid - 56; }
    const int ntn = N >> 6;
    const int k0 = (tile / ntn) * 64, n0 = (tile % ntn) * 64;
    const int t = threadIdx.x, tx = t & 63, ty = t >> 6;
    #pragma unroll
    for (int r = 0; r < 16; ++r) {
        const int kk = r * 4 + ty;
        ts[kk][tx] = src[(size_t)(k0 + kk) * N + n0 + tx];
    }
    __syncthreads();
    #pragma unroll
    for (int r = 0; r < 16; ++r) {
        const int nn = r * 4 + ty;
        dst[(size_t)(n0 + nn) * 256 + k0 + tx] = (_Float16)ts[tx][nn];
    }
}

// ---------------------------------------------------------------------------
// GEMM core: acc[4][4] += A[128 rows at m0][256] @ Bt[128 rows at n0][256]^T
// Bt is pre-transposed f16 [n][k]. AT in {float, _Float16}.
// ---------------------------------------------------------------------------
template<typename AT>
__device__ __forceinline__ void gemm_core(
    _Float16* __restrict__ As, _Float16* __restrict__ Bs,
    const AT* __restrict__ A, const _Float16* __restrict__ Bt,
    int m0, int n0, f32x4 (&acc)[4][4])
{
    const int t    = threadIdx.x;
    const int lane = t & 63, wid = t >> 6;
    const int wr = wid >> 1, wc = wid & 1;
    const int lr = lane & 15, lkb = (lane >> 4) * 8;
    const int arow = t >> 1, akoff = (t & 1) * 16;
    const int bn = t & 127, bkoff = (t >> 7) * 16;

    for (int kt = 0; kt < 256; kt += 32) {
        if constexpr (sizeof(AT) == 4) {
            const float* ap = (const float*)A + (size_t)(m0 + arow) * 256 + kt + akoff;
            float v[16];
            #pragma unroll
            for (int i = 0; i < 4; ++i) {
                float4 f = ((const float4*)ap)[i];
                v[4*i] = f.x; v[4*i+1] = f.y; v[4*i+2] = f.z; v[4*i+3] = f.w;
            }
            half8 h0, h1;
            #pragma unroll
            for (int i = 0; i < 8; ++i) { h0[i] = (_Float16)v[i]; h1[i] = (_Float16)v[8+i]; }
            *(half8*)&As[arow*LDT + akoff]     = h0;
            *(half8*)&As[arow*LDT + akoff + 8] = h1;
        } else {
            const _Float16* ap = (const _Float16*)A + (size_t)(m0 + arow) * 256 + kt + akoff;
            *(half8*)&As[arow*LDT + akoff]     = ((const half8*)ap)[0];
            *(half8*)&As[arow*LDT + akoff + 8] = ((const half8*)ap)[1];
        }
        {
            const _Float16* bp = Bt + (size_t)(n0 + bn) * 256 + kt + bkoff;
            *(half8*)&Bs[bn*LDT + bkoff]     = ((const half8*)bp)[0];
            *(half8*)&Bs[bn*LDT + bkoff + 8] = ((const half8*)bp)[1];
        }
        __syncthreads();

        half8 af[4], bf[4];
        #pragma unroll
        for (int m = 0; m < 4; ++m)
            af[m] = *(const half8*)&As[(wr*64 + m*16 + lr)*LDT + lkb];
        #pragma unroll
        for (int n = 0; n < 4; ++n)
            bf[n] = *(const half8*)&Bs[(wc*64 + n*16 + lr)*LDT + lkb];
        #pragma unroll
        for (int m = 0; m < 4; ++m)
            #pragma unroll
            for (int n = 0; n < 4; ++n)
                acc[m][n] = __builtin_amdgcn_mfma_f32_16x16x32_f16(af[m], bf[n], acc[m][n], 0, 0, 0);
        __syncthreads();
    }
}

// f16 store epilogue; col = n0 + local col (pass n0=0 to store at local cols)
__device__ __forceinline__ void epi_f16(
    f32x4 (&acc)[4][4], const float* __restrict__ bias,
    _Float16* __restrict__ C, int N, int m0, int n0)
{
    const int t = threadIdx.x, lane = t & 63, wid = t >> 6;
    const int wr = wid >> 1, wc = wid & 1, lr = lane & 15;
    #pragma unroll
    for (int n = 0; n < 4; ++n) {
        const int col = n0 + wc*64 + n*16 + lr;
        const float bv = bias[col];
        #pragma unroll
        for (int m = 0; m < 4; ++m)
            #pragma unroll
            for (int r = 0; r < 4; ++r) {
                const int row = m0 + wr*64 + m*16 + (lane >> 4)*4 + r;
                C[(size_t)row * N + col] = (_Float16)(acc[m][n][r] + bv);
            }
    }
}

// D1: z GEMM (by<128) + all 4 wp GEMMs (by>=128)
__global__ __launch_bounds__(256) void gemm_z_wp(
    const float* __restrict__ q, const _Float16* __restrict__ Wzt,
    const float* __restrict__ bz, _Float16* __restrict__ z,
    const float* __restrict__ f0, const float* __restrict__ f1,
    const float* __restrict__ f2, const float* __restrict__ f3,
    const _Float16* __restrict__ Wpt, const float* __restrict__ bp,
    _Float16* __restrict__ w0, _Float16* __restrict__ w1,
    _Float16* __restrict__ w2, _Float16* __restrict__ w3)
{
    __shared__ _Float16 As[128 * LDT];
    __shared__ _Float16 Bs[128 * LDT];
    const int by = blockIdx.y, bx = blockIdx.x;
    f32x4 acc[4][4] = {};
    const float* A; _Float16* C; const _Float16* Bt; const float* bias; int m0;
    if (by < 128) { A = q; C = z; Bt = Wzt; bias = bz; m0 = by * 128; }
    else {
        const int y = by - 128; Bt = Wpt; bias = bp;
        if      (y < 128) { A = f0; C = w0; m0 = y * 128; }
        else if (y < 160) { A = f1; C = w1; m0 = (y - 128) * 128; }
        else if (y < 168) { A = f2; C = w2; m0 = (y - 160) * 128; }
        else              { A = f3; C = w3; m0 = (y - 168) * 128; }
    }
    gemm_core<float>(As, Bs, A, Bt, m0, bx * 128, acc);
    epi_f16(acc, bias, C, 256, m0, bx * 128);
}

// D2: zo GEMM (bx<2) + za GEMM (bx==2), pure GEMM, no fused softmax
__global__ __launch_bounds__(256) void gemm_zo_za(
    const _Float16* __restrict__ z, const _Float16* __restrict__ Woat,
    const float* __restrict__ bo, const float* __restrict__ ba,
    _Float16* __restrict__ zo, _Float16* __restrict__ za)
{
    __shared__ _Float16 As[128 * LDT];
    __shared__ _Float16 Bs[128 * LDT];
    const int bx = blockIdx.x, by = blockIdx.y;
    const int m0 = by * 128;
    f32x4 acc[4][4] = {};
    gemm_core<_Float16>(As, Bs, z, Woat, m0, bx * 128, acc);
    if (bx < 2) {
        epi_f16(acc, bo, zo, 256, m0, bx * 128);
    } else {
        // acc holds Woat rows 256..383 (= Wa cols 0..127); store za local cols 0..127
        epi_f16(acc, ba, za, 128, m0, 0);
    }
}

// D3: softmax over s=16; za f16 [b][q][128] -> attn f16 [b][p][m][16]
__global__ __launch_bounds__(256) void softmax3(const _Float16* __restrict__ za, _Float16* __restrict__ attn)
{
    const int tid  = blockIdx.x * 256 + threadIdx.x;  // (b*4096+qpos)*8 + m
    const int m    = tid & 7;
    const int row  = tid >> 3;  // b*4096 + qpos
    const half8* zp = (const half8*)(za + (size_t)row * 128 + m * 16);
    const half8 a = zp[0], bvec = zp[1];
    float v[16];
    #pragma unroll
    for (int i = 0; i < 8; ++i) { v[i] = (float)a[i]; v[8+i] = (float)bvec[i]; }
    float mx = v[0];
    #pragma unroll
    for (int i = 1; i < 16; ++i) mx = fmaxf(mx, v[i]);
    float s = 0.f;
    #pragma unroll
    for (int i = 0; i < 16; ++i) { v[i] = expf(v[i] - mx); s += v[i]; }
    const float inv = 1.f / s;
    half8 o0, o1;
    #pragma unroll
    for (int i = 0; i < 8; ++i) { o0[i] = (_Float16)(v[i] * inv); o1[i] = (_Float16)(v[8+i] * inv); }
    half8* op = (half8*)(attn + ((size_t)row * 8 + m) * 16);
    op[0] = o0; op[1] = o1;
}

// D4: sample7. Block = 2 queries (XCD-swizzled); t = l*64 + qp*32 + m*4 + q.
// q = 16B-quarter of the 64B m-slice (NOT k). The 4-lane cluster (q=0..3)
// processes all 4 k-samples of (query,m,l) SEQUENTIALLY; per tap, the
// cluster's 4 lanes load the tap's 64B slice as 4x16B -> exactly ONE cache
// segment per load instruction per cluster (was ~4), and attn loads drop
// from ~16 scattered segments to 2. Dot partials pair-reduced via shfl_xor.
__global__ __launch_bounds__(256) void sample7(
    const _Float16* __restrict__ zo,    // f16 [b][qy][qx][256]
    const _Float16* __restrict__ attn,  // f16 [b][p][m][16]
    const float* __restrict__ ref,      // f32 [BS][64][64][2]
    const _Float16* __restrict__ wp0, const _Float16* __restrict__ wp1,
    const _Float16* __restrict__ wp2, const _Float16* __restrict__ wp3,
    _Float16* __restrict__ outp)        // f16 [b][p][256]
{
    const int bid = blockIdx.x;
    const int bp_ = (bid & 7) * 1024 + (bid >> 3);   // XCD-contiguous bands
    const int t  = threadIdx.x;
    const int q  = t & 3;                // quarter index (and own-k for store)
    const int m  = (t >> 2) & 7;
    const int qp = (t >> 5) & 1;
    const int l  = t >> 6;               // wave-uniform

    const int query = bp_ * 2 + qp;      // b*4096 + qy*64 + qx
    const int qx = query & 63;
    const int qy = (query >> 6) & 63;
    const int b  = query >> 12;

    const int ya = qy >> 2, yb = qy & 3;
    const int cb = m * 32 + yb * 8 + l * 2;

    const int hw = 64 >> l;
    const float fw = (float)hw;
    const _Float16* wp = (l == 0) ? wp0 : (l == 1) ? wp1 : (l == 2) ? wp2 : wp3;

    // all 4 k-offset pairs for (m,l): contiguous 16B, broadcast within cluster
    const uint4 offs = *(const uint4*)(zo + (size_t)query * 256 + (m * 4 + l) * 8);

    const int rb = m & 3;
    const float2 rr = *(const float2*)(ref + ((size_t)(rb * 4096) + qy * 64 + qx) * 2);
    const float pbx = rr.x * (fw - 1.f);
    const float pby = rr.y * (fw - 1.f);

    // per-sample coords (identical across the cluster's 4 lanes)
    int ix0[4], iy0[4];
    float wx0a[4], wx1a[4], wy0a[4], wy1a[4];
    const unsigned offw[4] = {offs.x, offs.y, offs.z, offs.w};
    #pragma unroll
    for (int kk = 0; kk < 4; ++kk) {
        const half2t oh = __builtin_bit_cast(half2t, offw[kk]);
        const float px  = pbx + (float)oh.x;
        const float py  = pby + (float)oh.y;
        const float gx  = 2.f * px / (fw - 1.f) - 1.f;
        const float gy  = 2.f * py / (fw - 1.f) - 1.f;
        const float xim = (gx + 1.f) * (fw * 0.5f) - 0.5f;
        const float yim = (gy + 1.f) * (fw * 0.5f) - 0.5f;
        const float x0f = floorf(xim), y0f = floorf(yim);
        wx1a[kk] = xim - x0f; wy1a[kk] = yim - y0f;
        wx0a[kk] = 1.f - wx1a[kk]; wy0a[kk] = 1.f - wy1a[kk];
        ix0[kk] = (int)x0f; iy0[kk] = (int)y0f;
    }

    const int sq = (q & 1) * 8;          // lane's s-range base within 16
    float res0 = 0.f, res1 = 0.f;

    #pragma unroll
    for (int kk = 0; kk < 4; ++kk) {
        const int p = (kk << 10) | (qx << 4) | ya;
        // attn: lane's 8 s-values (16B); lanes q0/q2 share a segment, q1/q3 share
        const uint4 wa = *(const uint4*)(attn + (((size_t)b * 4096 + p) * 8 + m) * 16 + sq);
        const half2t w0 = __builtin_bit_cast(half2t, wa.x);
        const half2t w1 = __builtin_bit_cast(half2t, wa.y);
        const half2t w2 = __builtin_bit_cast(half2t, wa.z);
        const half2t w3 = __builtin_bit_cast(half2t, wa.w);

        float r = 0.f;
        #pragma unroll
        for (int tap = 0; tap < 4; ++tap) {
            int iy = iy0[kk] + (tap >> 1);
            int ix = ix0[kk] + (tap & 1);
            const bool ok = (iy >= 0) & (iy < hw) & (ix >= 0) & (ix < hw);
            float wt = ((tap >> 1) ? wy1a[kk] : wy0a[kk]) * ((tap & 1) ? wx1a[kk] : wx0a[kk]);
            wt = ok ? wt : 0.f;
            iy = min(max(iy, 0), hw - 1);
            ix = min(max(ix, 0), hw - 1);
            // cluster-coalesced: 4 lanes cover the tap's 64B slice
            const uint4 u = *(const uint4*)(wp + (((size_t)b * hw + iy) * hw + ix) * 256 + m * 32 + q * 8);
            float d = 0.f;
            d = fdot2f(__builtin_bit_cast(half2t, u.x), w0, d);
            d = fdot2f(__builtin_bit_cast(half2t, u.y), w1, d);
            d = fdot2f(__builtin_bit_cast(half2t, u.z), w2, d);
            d = fdot2f(__builtin_bit_cast(half2t, u.w), w3, d);
            r += wt * d;
        }
        // pair-reduce: r2 = full dot for this lane's hi; rx = the other hi
        const float r2 = r + __shfl_xor(r, 1, 64);
        const float rx = __shfl_xor(r2, 2, 64);
        const float h0 = (q < 2) ? r2 : rx;
        const float h1 = (q < 2) ? rx : r2;
        if (kk == q) { res0 = h0; res1 = h1; }
    }

    const int pown = (q << 10) | (qx << 4) | ya;
    half2t o; o.x = (_Float16)res0; o.y = (_Float16)res1;
    *(half2t*)(outp + ((size_t)b * 4096 + pown) * 256 + cb) = o;
}

// D5: final GEMM (f16 A, f32 out)
__global__ __launch_bounds__(256) void gemm_final(
    const _Float16* __restrict__ A, const _Float16* __restrict__ Wmt,
    const float* __restrict__ bias, float* __restrict__ C)
{
    __shared__ _Float16 As[128 * LDT];
    __shared__ _Float16 Bs[128 * LDT];
    const int m0 = blockIdx.y * 128, n0 = blockIdx.x * 128;
    f32x4 acc[4][4] = {};
    gemm_core<_Float16>(As, Bs, A, Wmt, m0, n0, acc);
    const int t = threadIdx.x, lane = t & 63, wid = t >> 6;
    const int wr = wid >> 1, wc = wid & 1, lr = lane & 15;
    #pragma unroll
    for (int n = 0; n < 4; ++n) {
        const int col = n0 + wc*64 + n*16 + lr;
        const float bv = bias[col];
        #pragma unroll
        for (int m = 0; m < 4; ++m)
            #pragma unroll
            for (int r = 0; r < 4; ++r) {
                const int row = m0 + wr*64 + m*16 + (lane >> 4)*4 + r;
                C[(size_t)row * 256 + col] = acc[m][n][r] + bv;
            }
    }
}

extern "C" void kernel_launch(void* const* d_in, const int* in_sizes, int n_in,
                              void* d_out, int out_size, void* d_ws, size_t ws_size,
                              hipStream_t stream)
{
    const float* q   = (const float*)d_in[0];
    const float* ref = (const float*)d_in[1];
    const float* f0  = (const float*)d_in[2];
    const float* f1  = (const float*)d_in[3];
    const float* f2  = (const float*)d_in[4];
    const float* f3  = (const float*)d_in[5];
    const float* Wz  = (const float*)d_in[6];
    const float* bz  = (const float*)d_in[7];
    const float* Wo  = (const float*)d_in[8];
    const float* bo  = (const float*)d_in[9];
    const float* Wa  = (const float*)d_in[10];
    const float* ba  = (const float*)d_in[11];
    const float* Wp  = (const float*)d_in[12];
    const float* bp  = (const float*)d_in[13];
    const float* Wm  = (const float*)d_in[14];
    const float* bm  = (const float*)d_in[15];
    float* out = (float*)d_out;

    char* ws = (char*)d_ws;
    _Float16* z    = (_Float16*)(ws + ((size_t)0));          // f16 8MB
    _Float16* zo   = (_Float16*)(ws + ((size_t)16 << 20));   // f16 8MB
    _Float16* attn = (_Float16*)(ws + ((size_t)24 << 20));   // f16 4MB
    _Float16* wp0  = (_Float16*)(ws + ((size_t)28 << 20));   // f16 8MB
    _Float16* wp1  = (_Float16*)(ws + ((size_t)36 << 20));   // f16 2MB
    _Float16* wp2  = (_Float16*)(ws + ((size_t)38 << 20));   // f16 0.5MB
    _Float16* wp3  = (_Float16*)(ws + ((size_t)38 << 20) + ((size_t)512 << 10)); // 0.125MB
    _Float16* Wzt  = (_Float16*)(ws + ((size_t)40 << 20));                       // 128KB
    _Float16* Woat = (_Float16*)(ws + ((size_t)40 << 20) + ((size_t)256 << 10)); // 192KB
    _Float16* Wpt  = (_Float16*)(ws + ((size_t)40 << 20) + ((size_t)768 << 10)); // 128KB
    _Float16* Wmt  = (_Float16*)(ws + ((size_t)41 << 20));                       // 128KB
    _Float16* za   = (_Float16*)(ws + ((size_t)42 << 20));                       // 4MB
    _Float16* outp = z;  // f16 8MB, z dead after D2

    const dim3 blk(256);

    // D0: weights -> f16 transposed
    transpose_w<<<dim3(72), blk, 0, stream>>>(Wz, Wo, Wa, Wp, Wm, Wzt, Woat, Wpt, Wmt);
    // D1: z = f16(q@Wz+bz) AND wp_l = f16(feat_l@Wp+bp)
    gemm_z_wp<<<dim3(2, 298), blk, 0, stream>>>(q, Wzt, bz, z,
                                                f0, f1, f2, f3, Wpt, bp,
                                                wp0, wp1, wp2, wp3);
    // D2: zo = f16(z@Wo+bo) AND za = f16(z@Wa+ba)
    gemm_zo_za<<<dim3(3, 128), blk, 0, stream>>>(z, Woat, bo, ba, zo, za);
    // D3: softmax -> attn f16 [b][p][m][16]
    softmax3<<<dim3(512), blk, 0, stream>>>(za, attn);
    // D4: sampling -> out_pre f16 (overwrites z region)
    sample7<<<dim3(8192), blk, 0, stream>>>(zo, attn, ref, wp0, wp1, wp2, wp3, outp);
    // D5: out = out_pre@Wm+bm
    gemm_final<<<dim3(2, 128), blk, 0, stream>>>(outp, Wmt, bm, out);
}

// Round 11
// 96.105 us; speedup vs baseline: 1.0599x; 1.0599x over previous
//
#include <hip/hip_runtime.h>
#include <hip/hip_bf16.h>

// DeformableAttention: BS=4, Hq=Wq=64, C=256, M=8, K=4, L=4, CV=32
// SCALES = 64,32,16,8
//
// All-f16 pipeline, pre-transposed f16 weights, locality-optimized layouts:
//  D0 transpose_w: Wz,Wo,Wa,Wp,Wm (f32 [k][n]) -> f16 [n][k]
//  D1 gemm_z_wp : z = f16(q@Wz+bz)  AND  wp_l = f16(feat_l@Wp+bp)
//                 wp stored as per-(b,m) planes [(b*8+m)][hw*hw][32]
//                 -> adjacent-x pixels adjacent in memory (64B slices)
//  D2 gemm_zo_za: zo = f16(z@Wo+bo) AND za = f16(z@Wa+ba)
//  D3 softmax4  : za -> attn f16 [b][qx][ya][m][k][16]
//                 -> a (query,m) cluster's 4 k reads = one 128B run
//  D4 sample8   : sample6 thread map (lane owns (l,qp,m,k), 32ch via fdot2)
//  D5 gemm_final: out = out_pre@Wm+bm -> f32
//
// ws (MB): z/out_pre@0(8) zo@16(8) attn@24(4)
//   wp0@28(8) wp1@36(2) wp2@38(.5) wp3@38.5(.125)
//   Wzt@40 Woat@40.25 Wpt@40.75 Wmt@41 za@42(4). Peak ~46 MB.

typedef __attribute__((ext_vector_type(8))) _Float16 half8;
typedef __attribute__((ext_vector_type(2))) _Float16 half2t;
typedef __attribute__((ext_vector_type(4))) float f32x4;

constexpr int LDT = 40;  // LDS row stride (f16 elems) = 80B

#if __has_builtin(__builtin_amdgcn_fdot2)
__device__ __forceinline__ float fdot2f(half2t a, half2t b, float c) {
    return __builtin_amdgcn_fdot2(a, b, c, false);
}
#else
__device__ __forceinline__ float fdot2f(half2t a, half2t b, float c) {
    return c + (float)a.x * (float)b.x + (float)a.y * (float)b.y;
}
#endif

// ---------------------------------------------------------------------------
// D0: transpose+convert weights. 64x64 tiles via LDS. 72 blocks.
// ---------------------------------------------------------------------------
__global__ __launch_bounds__(256) void transpose_w(
    const float* __restrict__ Wz, const float* __restrict__ Wo,
    const float* __restrict__ Wa, const float* __restrict__ Wp,
    const float* __restrict__ Wm,
    _Float16* __restrict__ Wzt, _Float16* __restrict__ Woat,
    _Float16* __restrict__ Wpt, _Float16* __restrict__ Wmt)
{
    __shared__ float ts[64][65];
    const int bid = blockIdx.x;
    const float* src; _Float16* dst; int N, tile;
    if      (bid < 16) { src = Wz; dst = Wzt;          N = 256; tile = bid; }
    else if (bid < 32) { src = Wo; dst = Woat;         N = 256; tile = bid - 16; }
    else if (bid < 40) { src = Wa; dst = Woat + 65536; N = 128; tile = bid - 32; }
    else if (bid < 56) { src = Wp; dst = Wpt;          N = 256; tile = bid - 40; }
    else               { src = Wm; dst = Wmt;          N = 256; tile = bid - 56; }
    const int ntn = N >> 6;
    const int k0 = (tile / ntn) * 64, n0 = (tile % ntn) * 64;
    const int t = threadIdx.x, tx = t & 63, ty = t >> 6;
    #pragma unroll
    for (int r = 0; r < 16; ++r) {
        const int kk = r * 4 + ty;
        ts[kk][tx] = src[(size_t)(k0 + kk) * N + n0 + tx];
    }
    __syncthreads();
    #pragma unroll
    for (int r = 0; r < 16; ++r) {
        const int nn = r * 4 + ty;
        dst[(size_t)(n0 + nn) * 256 + k0 + tx] = (_Float16)ts[tx][nn];
    }
}

// ---------------------------------------------------------------------------
// GEMM core: acc[4][4] += A[128 rows at m0][256] @ Bt[128 rows at n0][256]^T
// ---------------------------------------------------------------------------
template<typename AT>
__device__ __forceinline__ void gemm_core(
    _Float16* __restrict__ As, _Float16* __restrict__ Bs,
    const AT* __restrict__ A, const _Float16* __restrict__ Bt,
    int m0, int n0, f32x4 (&acc)[4][4])
{
    const int t    = threadIdx.x;
    const int lane = t & 63, wid = t >> 6;
    const int wr = wid >> 1, wc = wid & 1;
    const int lr = lane & 15, lkb = (lane >> 4) * 8;
    const int arow = t >> 1, akoff = (t & 1) * 16;
    const int bn = t & 127, bkoff = (t >> 7) * 16;

    for (int kt = 0; kt < 256; kt += 32) {
        if constexpr (sizeof(AT) == 4) {
            const float* ap = (const float*)A + (size_t)(m0 + arow) * 256 + kt + akoff;
            float v[16];
            #pragma unroll
            for (int i = 0; i < 4; ++i) {
                float4 f = ((const float4*)ap)[i];
                v[4*i] = f.x; v[4*i+1] = f.y; v[4*i+2] = f.z; v[4*i+3] = f.w;
            }
            half8 h0, h1;
            #pragma unroll
            for (int i = 0; i < 8; ++i) { h0[i] = (_Float16)v[i]; h1[i] = (_Float16)v[8+i]; }
            *(half8*)&As[arow*LDT + akoff]     = h0;
            *(half8*)&As[arow*LDT + akoff + 8] = h1;
        } else {
            const _Float16* ap = (const _Float16*)A + (size_t)(m0 + arow) * 256 + kt + akoff;
            *(half8*)&As[arow*LDT + akoff]     = ((const half8*)ap)[0];
            *(half8*)&As[arow*LDT + akoff + 8] = ((const half8*)ap)[1];
        }
        {
            const _Float16* bp = Bt + (size_t)(n0 + bn) * 256 + kt + bkoff;
            *(half8*)&Bs[bn*LDT + bkoff]     = ((const half8*)bp)[0];
            *(half8*)&Bs[bn*LDT + bkoff + 8] = ((const half8*)bp)[1];
        }
        __syncthreads();

        half8 af[4], bf[4];
        #pragma unroll
        for (int m = 0; m < 4; ++m)
            af[m] = *(const half8*)&As[(wr*64 + m*16 + lr)*LDT + lkb];
        #pragma unroll
        for (int n = 0; n < 4; ++n)
            bf[n] = *(const half8*)&Bs[(wc*64 + n*16 + lr)*LDT + lkb];
        #pragma unroll
        for (int m = 0; m < 4; ++m)
            #pragma unroll
            for (int n = 0; n < 4; ++n)
                acc[m][n] = __builtin_amdgcn_mfma_f32_16x16x32_f16(af[m], bf[n], acc[m][n], 0, 0, 0);
        __syncthreads();
    }
}

// f16 store epilogue (row-major [rows][N])
__device__ __forceinline__ void epi_f16(
    f32x4 (&acc)[4][4], const float* __restrict__ bias,
    _Float16* __restrict__ C, int N, int m0, int n0)
{
    const int t = threadIdx.x, lane = t & 63, wid = t >> 6;
    const int wr = wid >> 1, wc = wid & 1, lr = lane & 15;
    #pragma unroll
    for (int n = 0; n < 4; ++n) {
        const int col = n0 + wc*64 + n*16 + lr;
        const float bv = bias[col];
        #pragma unroll
        for (int m = 0; m < 4; ++m)
            #pragma unroll
            for (int r = 0; r < 4; ++r) {
                const int row = m0 + wr*64 + m*16 + (lane >> 4)*4 + r;
                C[(size_t)row * N + col] = (_Float16)(acc[m][n][r] + bv);
            }
    }
}

// wp store epilogue: plane layout C[((b*8+mh)<<shift) + pix][32], cv = col&31.
// row = b<<shift | pix (level's flattened pixel row); col = mh*32 + cv.
__device__ __forceinline__ void epi_wp(
    f32x4 (&acc)[4][4], const float* __restrict__ bias,
    _Float16* __restrict__ C, int m0, int n0, int shift)
{
    const int t = threadIdx.x, lane = t & 63, wid = t >> 6;
    const int wr = wid >> 1, wc = wid & 1, lr = lane & 15;
    const int mask = (1 << shift) - 1;
    #pragma unroll
    for (int n = 0; n < 4; ++n) {
        const int col = n0 + wc*64 + n*16 + lr;
        const float bv = bias[col];
        const int mh = col >> 5, cv = col & 31;
        #pragma unroll
        for (int m = 0; m < 4; ++m)
            #pragma unroll
            for (int r = 0; r < 4; ++r) {
                const int row = m0 + wr*64 + m*16 + (lane >> 4)*4 + r;
                const int bb = row >> shift, pix = row & mask;
                C[((((size_t)(bb * 8 + mh)) << shift) + pix) * 32 + cv] =
                    (_Float16)(acc[m][n][r] + bv);
            }
    }
}

// D1: z GEMM (by<128) + all 4 wp GEMMs (by>=128, plane-layout stores)
__global__ __launch_bounds__(256) void gemm_z_wp(
    const float* __restrict__ q, const _Float16* __restrict__ Wzt,
    const float* __restrict__ bz, _Float16* __restrict__ z,
    const float* __restrict__ f0, const float* __restrict__ f1,
    const float* __restrict__ f2, const float* __restrict__ f3,
    const _Float16* __restrict__ Wpt, const float* __restrict__ bp,
    _Float16* __restrict__ w0, _Float16* __restrict__ w1,
    _Float16* __restrict__ w2, _Float16* __restrict__ w3)
{
    __shared__ _Float16 As[128 * LDT];
    __shared__ _Float16 Bs[128 * LDT];
    const int by = blockIdx.y, bx = blockIdx.x;
    f32x4 acc[4][4] = {};
    if (by < 128) {
        gemm_core<float>(As, Bs, q, Wzt, by * 128, bx * 128, acc);
        epi_f16(acc, bz, z, 256, by * 128, bx * 128);
    } else {
        const int y = by - 128;
        const float* A; _Float16* C; int m0, shift;
        if      (y < 128) { A = f0; C = w0; m0 = y * 128;         shift = 12; }
        else if (y < 160) { A = f1; C = w1; m0 = (y - 128) * 128; shift = 10; }
        else if (y < 168) { A = f2; C = w2; m0 = (y - 160) * 128; shift = 8;  }
        else              { A = f3; C = w3; m0 = (y - 168) * 128; shift = 6;  }
        gemm_core<float>(As, Bs, A, Wpt, m0, bx * 128, acc);
        epi_wp(acc, bp, C, m0, bx * 128, shift);
    }
}

// D2: zo GEMM (bx<2) + za GEMM (bx==2)
__global__ __launch_bounds__(256) void gemm_zo_za(
    const _Float16* __restrict__ z, const _Float16* __restrict__ Woat,
    const float* __restrict__ bo, const float* __restrict__ ba,
    _Float16* __restrict__ zo, _Float16* __restrict__ za)
{
    __shared__ _Float16 As[128 * LDT];
    __shared__ _Float16 Bs[128 * LDT];
    const int bx = blockIdx.x, by = blockIdx.y;
    const int m0 = by * 128;
    f32x4 acc[4][4] = {};
    gemm_core<_Float16>(As, Bs, z, Woat, m0, bx * 128, acc);
    if (bx < 2) {
        epi_f16(acc, bo, zo, 256, m0, bx * 128);
    } else {
        epi_f16(acc, ba, za, 128, m0, 0);
    }
}

// D3: softmax over s=16; za f16 [b][q][128] -> attn f16 [b][qx][ya][m][k][16]
__global__ __launch_bounds__(256) void softmax4(const _Float16* __restrict__ za, _Float16* __restrict__ attn)
{
    const int tid  = blockIdx.x * 256 + threadIdx.x;  // (b*4096+qpos)*8 + m
    const int m    = tid & 7;
    const int row  = tid >> 3;          // b*4096 + qpos
    const int qpos = row & 4095;
    const int b    = row >> 12;
    const int k    = qpos >> 10;
    const int qx   = (qpos >> 4) & 63;
    const int ya   = qpos & 15;
    const half8* zp = (const half8*)(za + (size_t)row * 128 + m * 16);
    const half8 a = zp[0], bvec = zp[1];
    float v[16];
    #pragma unroll
    for (int i = 0; i < 8; ++i) { v[i] = (float)a[i]; v[8+i] = (float)bvec[i]; }
    float mx = v[0];
    #pragma unroll
    for (int i = 1; i < 16; ++i) mx = fmaxf(mx, v[i]);
    float s = 0.f;
    #pragma unroll
    for (int i = 0; i < 16; ++i) { v[i] = expf(v[i] - mx); s += v[i]; }
    const float inv = 1.f / s;
    half8 o0, o1;
    #pragma unroll
    for (int i = 0; i < 8; ++i) { o0[i] = (_Float16)(v[i] * inv); o1[i] = (_Float16)(v[8+i] * inv); }
    half8* op = (half8*)(attn + ((((((size_t)b * 64 + qx) * 16 + ya) * 8 + m) * 4 + k) * 16));
    op[0] = o0; op[1] = o1;
}

// D4: sample8. Block = 2 queries (XCD-swizzled); t = l*64 + qp*32 + m*4 + k.
// Wave = one level; 4-lane cluster = k per (qp,m). wp plane layout puts the
// cluster's tap footprint into ~3 contiguous runs; attn layout puts its 4 k
// vectors in one 128B run.
__global__ __launch_bounds__(256) void sample8(
    const _Float16* __restrict__ zo,    // f16 [b][qy][qx][256]
    const _Float16* __restrict__ attn,  // f16 [b][qx][ya][m][k][16]
    const float* __restrict__ ref,      // f32 [BS][64][64][2]
    const _Float16* __restrict__ wp0, const _Float16* __restrict__ wp1,
    const _Float16* __restrict__ wp2, const _Float16* __restrict__ wp3,
    _Float16* __restrict__ outp)        // f16 [b][p][256]
{
    const int bid = blockIdx.x;
    const int bp_ = (bid & 7) * 1024 + (bid >> 3);   // XCD-contiguous bands
    const int t  = threadIdx.x;
    const int k  = t & 3;
    const int m  = (t >> 2) & 7;
    const int qp = (t >> 5) & 1;
    const int l  = t >> 6;               // wave-uniform

    const int query = bp_ * 2 + qp;      // b*4096 + qy*64 + qx
    const int qx = query & 63;
    const int qy = (query >> 6) & 63;
    const int b  = query >> 12;

    const int ya = qy >> 2, yb = qy & 3;
    const int p  = (k << 10) | (qx << 4) | ya;
    const int cb = m * 32 + yb * 8 + l * 2;

    const int hw = 64 >> l;
    const int shift = 12 - 2 * l;        // log2(hw*hw)
    const float fw = (float)hw;
    const _Float16* wp = (l == 0) ? wp0 : (l == 1) ? wp1 : (l == 2) ? wp2 : wp3;

    const unsigned off2 = *(const unsigned*)(zo + (size_t)query * 256 + ((m * 4 + l) * 4 + k) * 2);
    const half2t offh = __builtin_bit_cast(half2t, off2);
    const float offx = (float)offh.x;
    const float offy = (float)offh.y;

    const int rb = m & 3;
    const float2 rr = *(const float2*)(ref + ((size_t)(rb * 4096) + qy * 64 + qx) * 2);

    const float px  = rr.x * (fw - 1.f) + offx;
    const float py  = rr.y * (fw - 1.f) + offy;
    const float gx  = 2.f * px / (fw - 1.f) - 1.f;
    const float gy  = 2.f * py / (fw - 1.f) - 1.f;
    const float xim = (gx + 1.f) * (fw * 0.5f) - 0.5f;
    const float yim = (gy + 1.f) * (fw * 0.5f) - 0.5f;

    const float x0f = floorf(xim), y0f = floorf(yim);
    const float wx1 = xim - x0f, wy1 = yim - y0f;
    const float wx0 = 1.f - wx1, wy0 = 1.f - wy1;
    const int ix0 = (int)x0f, iy0 = (int)y0f;

    // attn: lane's own k vector; cluster's 4 lanes = one 128B contiguous run
    half2t w[8];
    {
        const uint4* ap = (const uint4*)(attn +
            ((((((size_t)b * 64 + qx) * 16 + ya) * 8 + m) * 4 + k) * 16));
        const uint4 wa = ap[0], wb = ap[1];
        w[0] = __builtin_bit_cast(half2t, wa.x); w[1] = __builtin_bit_cast(half2t, wa.y);
        w[2] = __builtin_bit_cast(half2t, wa.z); w[3] = __builtin_bit_cast(half2t, wa.w);
        w[4] = __builtin_bit_cast(half2t, wb.x); w[5] = __builtin_bit_cast(half2t, wb.y);
        w[6] = __builtin_bit_cast(half2t, wb.z); w[7] = __builtin_bit_cast(half2t, wb.w);
    }

    // wp plane for (b,m)
    const _Float16* plane = wp + ((((size_t)(b * 8 + m)) << shift) * 32);

    float r0 = 0.f, r1 = 0.f;
    #pragma unroll
    for (int tap = 0; tap < 4; ++tap) {
        int iy = iy0 + (tap >> 1);
        int ix = ix0 + (tap & 1);
        const bool ok = (iy >= 0) & (iy < hw) & (ix >= 0) & (ix < hw);
        float wt = ((tap >> 1) ? wy1 : wy0) * ((tap & 1) ? wx1 : wx0);
        wt = ok ? wt : 0.f;
        iy = min(max(iy, 0), hw - 1);
        ix = min(max(ix, 0), hw - 1);
        const uint4* tp = (const uint4*)(plane + ((size_t)(iy * hw + ix)) * 32);
        const uint4 u0 = tp[0], u1 = tp[1], u2 = tp[2], u3 = tp[3];
        float d0 = 0.f, d1 = 0.f;
        d0 = fdot2f(__builtin_bit_cast(half2t, u0.x), w[0], d0);
        d0 = fdot2f(__builtin_bit_cast(half2t, u0.y), w[1], d0);
        d0 = fdot2f(__builtin_bit_cast(half2t, u0.z), w[2], d0);
        d0 = fdot2f(__builtin_bit_cast(half2t, u0.w), w[3], d0);
        d0 = fdot2f(__builtin_bit_cast(half2t, u1.x), w[4], d0);
        d0 = fdot2f(__builtin_bit_cast(half2t, u1.y), w[5], d0);
        d0 = fdot2f(__builtin_bit_cast(half2t, u1.z), w[6], d0);
        d0 = fdot2f(__builtin_bit_cast(half2t, u1.w), w[7], d0);
        d1 = fdot2f(__builtin_bit_cast(half2t, u2.x), w[0], d1);
        d1 = fdot2f(__builtin_bit_cast(half2t, u2.y), w[1], d1);
        d1 = fdot2f(__builtin_bit_cast(half2t, u2.z), w[2], d1);
        d1 = fdot2f(__builtin_bit_cast(half2t, u2.w), w[3], d1);
        d1 = fdot2f(__builtin_bit_cast(half2t, u3.x), w[4], d1);
        d1 = fdot2f(__builtin_bit_cast(half2t, u3.y), w[5], d1);
        d1 = fdot2f(__builtin_bit_cast(half2t, u3.z), w[6], d1);
        d1 = fdot2f(__builtin_bit_cast(half2t, u3.w), w[7], d1);
        r0 += wt * d0;
        r1 += wt * d1;
    }

    half2t o; o.x = (_Float16)r0; o.y = (_Float16)r1;
    *(half2t*)(outp + ((size_t)b * 4096 + p) * 256 + cb) = o;
}

// D5: final GEMM (f16 A, f32 out)
__global__ __launch_bounds__(256) void gemm_final(
    const _Float16* __restrict__ A, const _Float16* __restrict__ Wmt,
    const float* __restrict__ bias, float* __restrict__ C)
{
    __shared__ _Float16 As[128 * LDT];
    __shared__ _Float16 Bs[128 * LDT];
    const int m0 = blockIdx.y * 128, n0 = blockIdx.x * 128;
    f32x4 acc[4][4] = {};
    gemm_core<_Float16>(As, Bs, A, Wmt, m0, n0, acc);
    const int t = threadIdx.x, lane = t & 63, wid = t >> 6;
    const int wr = wid >> 1, wc = wid & 1, lr = lane & 15;
    #pragma unroll
    for (int n = 0; n < 4; ++n) {
        const int col = n0 + wc*64 + n*16 + lr;
        const float bv = bias[col];
        #pragma unroll
        for (int m = 0; m < 4; ++m)
            #pragma unroll
            for (int r = 0; r < 4; ++r) {
                const int row = m0 + wr*64 + m*16 + (lane >> 4)*4 + r;
                C[(size_t)row * 256 + col] = acc[m][n][r] + bv;
            }
    }
}

extern "C" void kernel_launch(void* const* d_in, const int* in_sizes, int n_in,
                              void* d_out, int out_size, void* d_ws, size_t ws_size,
                              hipStream_t stream)
{
    const float* q   = (const float*)d_in[0];
    const float* ref = (const float*)d_in[1];
    const float* f0  = (const float*)d_in[2];
    const float* f1  = (const float*)d_in[3];
    const float* f2  = (const float*)d_in[4];
    const float* f3  = (const float*)d_in[5];
    const float* Wz  = (const float*)d_in[6];
    const float* bz  = (const float*)d_in[7];
    const float* Wo  = (const float*)d_in[8];
    const float* bo  = (const float*)d_in[9];
    const float* Wa  = (const float*)d_in[10];
    const float* ba  = (const float*)d_in[11];
    const float* Wp  = (const float*)d_in[12];
    const float* bp  = (const float*)d_in[13];
    const float* Wm  = (const float*)d_in[14];
    const float* bm  = (const float*)d_in[15];
    float* out = (float*)d_out;

    char* ws = (char*)d_ws;
    _Float16* z    = (_Float16*)(ws + ((size_t)0));          // f16 8MB
    _Float16* zo   = (_Float16*)(ws + ((size_t)16 << 20));   // f16 8MB
    _Float16* attn = (_Float16*)(ws + ((size_t)24 << 20));   // f16 4MB
    _Float16* wp0  = (_Float16*)(ws + ((size_t)28 << 20));   // f16 8MB
    _Float16* wp1  = (_Float16*)(ws + ((size_t)36 << 20));   // f16 2MB
    _Float16* wp2  = (_Float16*)(ws + ((size_t)38 << 20));   // f16 0.5MB
    _Float16* wp3  = (_Float16*)(ws + ((size_t)38 << 20) + ((size_t)512 << 10)); // 0.125MB
    _Float16* Wzt  = (_Float16*)(ws + ((size_t)40 << 20));                       // 128KB
    _Float16* Woat = (_Float16*)(ws + ((size_t)40 << 20) + ((size_t)256 << 10)); // 192KB
    _Float16* Wpt  = (_Float16*)(ws + ((size_t)40 << 20) + ((size_t)768 << 10)); // 128KB
    _Float16* Wmt  = (_Float16*)(ws + ((size_t)41 << 20));                       // 128KB
    _Float16* za   = (_Float16*)(ws + ((size_t)42 << 20));                       // 4MB
    _Float16* outp = z;  // f16 8MB, z dead after D2

    const dim3 blk(256);

    // D0: weights -> f16 transposed
    transpose_w<<<dim3(72), blk, 0, stream>>>(Wz, Wo, Wa, Wp, Wm, Wzt, Woat, Wpt, Wmt);
    // D1: z = f16(q@Wz+bz) AND wp_l = f16(feat_l@Wp+bp) (plane layout)
    gemm_z_wp<<<dim3(2, 298), blk, 0, stream>>>(q, Wzt, bz, z,
                                                f0, f1, f2, f3, Wpt, bp,
                                                wp0, wp1, wp2, wp3);
    // D2: zo = f16(z@Wo+bo) AND za = f16(z@Wa+ba)
    gemm_zo_za<<<dim3(3, 128), blk, 0, stream>>>(z, Woat, bo, ba, zo, za);
    // D3: softmax -> attn f16 [b][qx][ya][m][k][16]
    softmax4<<<dim3(512), blk, 0, stream>>>(za, attn);
    // D4: sampling -> out_pre f16 (overwrites z region)
    sample8<<<dim3(8192), blk, 0, stream>>>(zo, attn, ref, wp0, wp1, wp2, wp3, outp);
    // D5: out = out_pre@Wm+bm
    gemm_final<<<dim3(2, 128), blk, 0, stream>>>(outp, Wmt, bm, out);
}

// Round 12
// 94.763 us; speedup vs baseline: 1.0749x; 1.0142x over previous
//
#include <hip/hip_runtime.h>
#include <hip/hip_bf16.h>

// DeformableAttention: BS=4, Hq=Wq=64, C=256, M=8, K=4, L=4, CV=32
// SCALES = 64,32,16,8
//
// All-f16 pipeline, pre-transposed f16 weights, locality-optimized layouts:
//  D0 transpose_w: Wz,Wo,Wa,Wp,Wm (f32 [k][n]) -> f16 [n][k]
//  D1 gemm_z_wp : z = f16(q@Wz+bz)  AND  wp_l = f16(feat_l@Wp+bp)
//                 wp stored as per-(b,m) planes [(b*8+m)][hw*hw][32]
//  D2 gemm_zo_at: zo = f16(z@Wo+bo) with offset-channel permutation
//                 (c' = l*64+m*8+k*2+xy -> sample reads 128B runs), AND
//                 za blocks: LDS-transpose + register-local softmax -> attn
//                 f16 [b][qx][ya][m][k][16]  (no shfl, no za round-trip)
//  D4 sample8   : wave=level, cluster=k, 32ch/lane via fdot2
//  D5 gemm_final: out = out_pre@Wm+bm -> f32
//
// ws (MB): z/out_pre@0(8) zo@16(8) attn@24(4)
//   wp0@28(8) wp1@36(2) wp2@38(.5) wp3@38.5(.125)
//   Wzt@40 Woat@40.25 Wpt@40.75 Wmt@41. Peak ~41.25 MB.

typedef __attribute__((ext_vector_type(8))) _Float16 half8;
typedef __attribute__((ext_vector_type(2))) _Float16 half2t;
typedef __attribute__((ext_vector_type(4))) float f32x4;

constexpr int LDT = 40;  // LDS row stride (f16 elems) = 80B

#if __has_builtin(__builtin_amdgcn_fdot2)
__device__ __forceinline__ float fdot2f(half2t a, half2t b, float c) {
    return __builtin_amdgcn_fdot2(a, b, c, false);
}
#else
__device__ __forceinline__ float fdot2f(half2t a, half2t b, float c) {
    return c + (float)a.x * (float)b.x + (float)a.y * (float)b.y;
}
#endif

// ---------------------------------------------------------------------------
// D0: transpose+convert weights. 64x64 tiles via LDS. 72 blocks.
// ---------------------------------------------------------------------------
__global__ __launch_bounds__(256) void transpose_w(
    const float* __restrict__ Wz, const float* __restrict__ Wo,
    const float* __restrict__ Wa, const float* __restrict__ Wp,
    const float* __restrict__ Wm,
    _Float16* __restrict__ Wzt, _Float16* __restrict__ Woat,
    _Float16* __restrict__ Wpt, _Float16* __restrict__ Wmt)
{
    __shared__ float ts[64][65];
    const int bid = blockIdx.x;
    const float* src; _Float16* dst; int N, tile;
    if      (bid < 16) { src = Wz; dst = Wzt;          N = 256; tile = bid; }
    else if (bid < 32) { src = Wo; dst = Woat;         N = 256; tile = bid - 16; }
    else if (bid < 40) { src = Wa; dst = Woat + 65536; N = 128; tile = bid - 32; }
    else if (bid < 56) { src = Wp; dst = Wpt;          N = 256; tile = bid - 40; }
    else               { src = Wm; dst = Wmt;          N = 256; tile = bid - 56; }
    const int ntn = N >> 6;
    const int k0 = (tile / ntn) * 64, n0 = (tile % ntn) * 64;
    const int t = threadIdx.x, tx = t & 63, ty = t >> 6;
    #pragma unroll
    for (int r = 0; r < 16; ++r) {
        const int kk = r * 4 + ty;
        ts[kk][tx] = src[(size_t)(k0 + kk) * N + n0 + tx];
    }
    __syncthreads();
    #pragma unroll
    for (int r = 0; r < 16; ++r) {
        const int nn = r * 4 + ty;
        dst[(size_t)(n0 + nn) * 256 + k0 + tx] = (_Float16)ts[tx][nn];
    }
}

// ---------------------------------------------------------------------------
// GEMM core: acc[4][4] += A[128 rows at m0][256] @ Bt[128 rows at n0][256]^T
// ---------------------------------------------------------------------------
template<typename AT>
__device__ __forceinline__ void gemm_core(
    _Float16* __restrict__ As, _Float16* __restrict__ Bs,
    const AT* __restrict__ A, const _Float16* __restrict__ Bt,
    int m0, int n0, f32x4 (&acc)[4][4])
{
    const int t    = threadIdx.x;
    const int lane = t & 63, wid = t >> 6;
    const int wr = wid >> 1, wc = wid & 1;
    const int lr = lane & 15, lkb = (lane >> 4) * 8;
    const int arow = t >> 1, akoff = (t & 1) * 16;
    const int bn = t & 127, bkoff = (t >> 7) * 16;

    for (int kt = 0; kt < 256; kt += 32) {
        if constexpr (sizeof(AT) == 4) {
            const float* ap = (const float*)A + (size_t)(m0 + arow) * 256 + kt + akoff;
            float v[16];
            #pragma unroll
            for (int i = 0; i < 4; ++i) {
                float4 f = ((const float4*)ap)[i];
                v[4*i] = f.x; v[4*i+1] = f.y; v[4*i+2] = f.z; v[4*i+3] = f.w;
            }
            half8 h0, h1;
            #pragma unroll
            for (int i = 0; i < 8; ++i) { h0[i] = (_Float16)v[i]; h1[i] = (_Float16)v[8+i]; }
            *(half8*)&As[arow*LDT + akoff]     = h0;
            *(half8*)&As[arow*LDT + akoff + 8] = h1;
        } else {
            const _Float16* ap = (const _Float16*)A + (size_t)(m0 + arow) * 256 + kt + akoff;
            *(half8*)&As[arow*LDT + akoff]     = ((const half8*)ap)[0];
            *(half8*)&As[arow*LDT + akoff + 8] = ((const half8*)ap)[1];
        }
        {
            const _Float16* bp = Bt + (size_t)(n0 + bn) * 256 + kt + bkoff;
            *(half8*)&Bs[bn*LDT + bkoff]     = ((const half8*)bp)[0];
            *(half8*)&Bs[bn*LDT + bkoff + 8] = ((const half8*)bp)[1];
        }
        __syncthreads();

        half8 af[4], bf[4];
        #pragma unroll
        for (int m = 0; m < 4; ++m)
            af[m] = *(const half8*)&As[(wr*64 + m*16 + lr)*LDT + lkb];
        #pragma unroll
        for (int n = 0; n < 4; ++n)
            bf[n] = *(const half8*)&Bs[(wc*64 + n*16 + lr)*LDT + lkb];
        #pragma unroll
        for (int m = 0; m < 4; ++m)
            #pragma unroll
            for (int n = 0; n < 4; ++n)
                acc[m][n] = __builtin_amdgcn_mfma_f32_16x16x32_f16(af[m], bf[n], acc[m][n], 0, 0, 0);
        __syncthreads();
    }
}

// f16 store epilogue (row-major [rows][N])
__device__ __forceinline__ void epi_f16(
    f32x4 (&acc)[4][4], const float* __restrict__ bias,
    _Float16* __restrict__ C, int N, int m0, int n0)
{
    const int t = threadIdx.x, lane = t & 63, wid = t >> 6;
    const int wr = wid >> 1, wc = wid & 1, lr = lane & 15;
    #pragma unroll
    for (int n = 0; n < 4; ++n) {
        const int col = n0 + wc*64 + n*16 + lr;
        const float bv = bias[col];
        #pragma unroll
        for (int m = 0; m < 4; ++m)
            #pragma unroll
            for (int r = 0; r < 4; ++r) {
                const int row = m0 + wr*64 + m*16 + (lane >> 4)*4 + r;
                C[(size_t)row * N + col] = (_Float16)(acc[m][n][r] + bv);
            }
    }
}

// wp store epilogue: plane layout C[((b*8+mh)<<shift) + pix][32]
__device__ __forceinline__ void epi_wp(
    f32x4 (&acc)[4][4], const float* __restrict__ bias,
    _Float16* __restrict__ C, int m0, int n0, int shift)
{
    const int t = threadIdx.x, lane = t & 63, wid = t >> 6;
    const int wr = wid >> 1, wc = wid & 1, lr = lane & 15;
    const int mask = (1 << shift) - 1;
    #pragma unroll
    for (int n = 0; n < 4; ++n) {
        const int col = n0 + wc*64 + n*16 + lr;
        const float bv = bias[col];
        const int mh = col >> 5, cv = col & 31;
        #pragma unroll
        for (int m = 0; m < 4; ++m)
            #pragma unroll
            for (int r = 0; r < 4; ++r) {
                const int row = m0 + wr*64 + m*16 + (lane >> 4)*4 + r;
                const int bb = row >> shift, pix = row & mask;
                C[((((size_t)(bb * 8 + mh)) << shift) + pix) * 32 + cv] =
                    (_Float16)(acc[m][n][r] + bv);
            }
    }
}

// D1: z GEMM (by<128) + all 4 wp GEMMs (by>=128, plane-layout stores)
__global__ __launch_bounds__(256) void gemm_z_wp(
    const float* __restrict__ q, const _Float16* __restrict__ Wzt,
    const float* __restrict__ bz, _Float16* __restrict__ z,
    const float* __restrict__ f0, const float* __restrict__ f1,
    const float* __restrict__ f2, const float* __restrict__ f3,
    const _Float16* __restrict__ Wpt, const float* __restrict__ bp,
    _Float16* __restrict__ w0, _Float16* __restrict__ w1,
    _Float16* __restrict__ w2, _Float16* __restrict__ w3)
{
    __shared__ _Float16 As[128 * LDT];
    __shared__ _Float16 Bs[128 * LDT];
    const int by = blockIdx.y, bx = blockIdx.x;
    f32x4 acc[4][4] = {};
    if (by < 128) {
        gemm_core<float>(As, Bs, q, Wzt, by * 128, bx * 128, acc);
        epi_f16(acc, bz, z, 256, by * 128, bx * 128);
    } else {
        const int y = by - 128;
        const float* A; _Float16* C; int m0, shift;
        if      (y < 128) { A = f0; C = w0; m0 = y * 128;         shift = 12; }
        else if (y < 160) { A = f1; C = w1; m0 = (y - 128) * 128; shift = 10; }
        else if (y < 168) { A = f2; C = w2; m0 = (y - 160) * 128; shift = 8;  }
        else              { A = f3; C = w3; m0 = (y - 168) * 128; shift = 6;  }
        gemm_core<float>(As, Bs, A, Wpt, m0, bx * 128, acc);
        epi_wp(acc, bp, C, m0, bx * 128, shift);
    }
}

// D2: zo GEMM with channel permutation (bx<2) + za GEMM with fused
// LDS-transpose softmax (bx==2). LDS: smax[128][136] overlaid on As/Bs
// (both dead after gemm_core's final barrier). No cross-lane ops.
__global__ __launch_bounds__(256) void gemm_zo_at(
    const _Float16* __restrict__ z, const _Float16* __restrict__ Woat,
    const float* __restrict__ bo, const float* __restrict__ ba,
    _Float16* __restrict__ zo, _Float16* __restrict__ attn)
{
    __shared__ __align__(16) char ldsbuf[128 * 136 * 2];  // 34816B >= 2*128*LDT*2
    _Float16* As = (_Float16*)ldsbuf;
    _Float16* Bs = As + 128 * LDT;
    _Float16 (*smax)[136] = (_Float16(*)[136])ldsbuf;

    const int bx = blockIdx.x, by = blockIdx.y;
    const int m0 = by * 128;
    f32x4 acc[4][4] = {};
    gemm_core<_Float16>(As, Bs, z, Woat, m0, bx * 128, acc);

    const int t = threadIdx.x, lane = t & 63, wid = t >> 6;
    const int wr = wid >> 1, wc = wid & 1, lr = lane & 15;

    if (bx < 2) {
        // zo with offset-channel permutation: semantic c=(m,l,k,xy) stored at
        // c' = l*64 + m*8 + k*2 + xy  -> sample's wave reads 128B runs
        #pragma unroll
        for (int n = 0; n < 4; ++n) {
            const int c = bx * 128 + wc*64 + n*16 + lr;
            const float bv = bo[c];
            const int cp = (((c >> 3) & 3) << 6) | ((c >> 5) << 3)
                         | (((c >> 1) & 3) << 1) | (c & 1);
            #pragma unroll
            for (int m = 0; m < 4; ++m)
                #pragma unroll
                for (int r = 0; r < 4; ++r) {
                    const int row = m0 + wr*64 + m*16 + (lane >> 4)*4 + r;
                    zo[(size_t)row * 256 + cp] = (_Float16)(acc[m][n][r] + bv);
                }
        }
    } else {
        // 1) deposit acc+ba into LDS (f16), transposing ownership
        #pragma unroll
        for (int n = 0; n < 4; ++n) {
            const int col = wc*64 + n*16 + lr;      // 0..127 = mh*16+s
            const float bv = ba[col];
            #pragma unroll
            for (int m = 0; m < 4; ++m)
                #pragma unroll
                for (int r = 0; r < 4; ++r) {
                    const int rowl = wr*64 + m*16 + (lane >> 4)*4 + r;
                    smax[rowl][col] = (_Float16)(acc[m][n][r] + bv);
                }
        }
        __syncthreads();
        // 2) each thread: 4 (row,mh) groups, register-local softmax
        #pragma unroll
        for (int j = 0; j < 4; ++j) {
            const int g    = j * 256 + t;           // 0..1023
            const int rowl = g >> 3, mh = g & 7;
            const half8* sp = (const half8*)&smax[rowl][mh * 16];
            const half8 a = sp[0], bb8 = sp[1];
            float v[16];
            #pragma unroll
            for (int i = 0; i < 8; ++i) { v[i] = (float)a[i]; v[8+i] = (float)bb8[i]; }
            float mx = v[0];
            #pragma unroll
            for (int i = 1; i < 16; ++i) mx = fmaxf(mx, v[i]);
            float s = 0.f;
            #pragma unroll
            for (int i = 0; i < 16; ++i) { v[i] = expf(v[i] - mx); s += v[i]; }
            const float inv = 1.f / s;
            half8 o0, o1;
            #pragma unroll
            for (int i = 0; i < 8; ++i) { o0[i] = (_Float16)(v[i]*inv); o1[i] = (_Float16)(v[8+i]*inv); }
            const int row  = m0 + rowl;
            const int qpos = row & 4095, b = row >> 12;
            const int k = qpos >> 10, qx = (qpos >> 4) & 63, ya = qpos & 15;
            half8* op = (half8*)(attn +
                ((((((size_t)b * 64 + qx) * 16 + ya) * 8 + mh) * 4 + k) * 16));
            op[0] = o0; op[1] = o1;
        }
    }
}

// D4: sample8. Block = 2 queries (XCD-swizzled); t = l*64 + qp*32 + m*4 + k.
// Wave = one level; 4-lane cluster = k per (qp,m). wp plane layout; attn
// layout gives per-(query,m) 128B runs; zo permutation gives 128B offset runs.
__global__ __launch_bounds__(256) void sample8(
    const _Float16* __restrict__ zo,    // f16 [b][qy][qx][perm 256]
    const _Float16* __restrict__ attn,  // f16 [b][qx][ya][m][k][16]
    const float* __restrict__ ref,      // f32 [BS][64][64][2]
    const _Float16* __restrict__ wp0, const _Float16* __restrict__ wp1,
    const _Float16* __restrict__ wp2, const _Float16* __restrict__ wp3,
    _Float16* __restrict__ outp)        // f16 [b][p][256]
{
    const int bid = blockIdx.x;
    const int bp_ = (bid & 7) * 1024 + (bid >> 3);   // XCD-contiguous bands
    const int t  = threadIdx.x;
    const int k  = t & 3;
    const int m  = (t >> 2) & 7;
    const int qp = (t >> 5) & 1;
    const int l  = t >> 6;               // wave-uniform

    const int query = bp_ * 2 + qp;      // b*4096 + qy*64 + qx
    const int qx = query & 63;
    const int qy = (query >> 6) & 63;
    const int b  = query >> 12;

    const int ya = qy >> 2, yb = qy & 3;
    const int p  = (k << 10) | (qx << 4) | ya;
    const int cb = m * 32 + yb * 8 + l * 2;

    const int hw = 64 >> l;
    const int shift = 12 - 2 * l;        // log2(hw*hw)
    const float fw = (float)hw;
    const _Float16* wp = (l == 0) ? wp0 : (l == 1) ? wp1 : (l == 2) ? wp2 : wp3;

    // permuted offsets: wave's loads = per-query 128B contiguous runs
    const unsigned off2 = *(const unsigned*)(zo + (size_t)query * 256 + (l * 64 + m * 8 + k * 2));
    const half2t offh = __builtin_bit_cast(half2t, off2);
    const float offx = (float)offh.x;
    const float offy = (float)offh.y;

    const int rb = m & 3;
    const float2 rr = *(const float2*)(ref + ((size_t)(rb * 4096) + qy * 64 + qx) * 2);

    const float px  = rr.x * (fw - 1.f) + offx;
    const float py  = rr.y * (fw - 1.f) + offy;
    const float gx  = 2.f * px / (fw - 1.f) - 1.f;
    const float gy  = 2.f * py / (fw - 1.f) - 1.f;
    const float xim = (gx + 1.f) * (fw * 0.5f) - 0.5f;
    const float yim = (gy + 1.f) * (fw * 0.5f) - 0.5f;

    const float x0f = floorf(xim), y0f = floorf(yim);
    const float wx1 = xim - x0f, wy1 = yim - y0f;
    const float wx0 = 1.f - wx1, wy0 = 1.f - wy1;
    const int ix0 = (int)x0f, iy0 = (int)y0f;

    half2t w[8];
    {
        const uint4* ap = (const uint4*)(attn +
            ((((((size_t)b * 64 + qx) * 16 + ya) * 8 + m) * 4 + k) * 16));
        const uint4 wa = ap[0], wb = ap[1];
        w[0] = __builtin_bit_cast(half2t, wa.x); w[1] = __builtin_bit_cast(half2t, wa.y);
        w[2] = __builtin_bit_cast(half2t, wa.z); w[3] = __builtin_bit_cast(half2t, wa.w);
        w[4] = __builtin_bit_cast(half2t, wb.x); w[5] = __builtin_bit_cast(half2t, wb.y);
        w[6] = __builtin_bit_cast(half2t, wb.z); w[7] = __builtin_bit_cast(half2t, wb.w);
    }

    const _Float16* plane = wp + ((((size_t)(b * 8 + m)) << shift) * 32);

    float r0 = 0.f, r1 = 0.f;
    #pragma unroll
    for (int tap = 0; tap < 4; ++tap) {
        int iy = iy0 + (tap >> 1);
        int ix = ix0 + (tap & 1);
        const bool ok = (iy >= 0) & (iy < hw) & (ix >= 0) & (ix < hw);
        float wt = ((tap >> 1) ? wy1 : wy0) * ((tap & 1) ? wx1 : wx0);
        wt = ok ? wt : 0.f;
        iy = min(max(iy, 0), hw - 1);
        ix = min(max(ix, 0), hw - 1);
        const uint4* tp = (const uint4*)(plane + ((size_t)(iy * hw + ix)) * 32);
        const uint4 u0 = tp[0], u1 = tp[1], u2 = tp[2], u3 = tp[3];
        float d0 = 0.f, d1 = 0.f;
        d0 = fdot2f(__builtin_bit_cast(half2t, u0.x), w[0], d0);
        d0 = fdot2f(__builtin_bit_cast(half2t, u0.y), w[1], d0);
        d0 = fdot2f(__builtin_bit_cast(half2t, u0.z), w[2], d0);
        d0 = fdot2f(__builtin_bit_cast(half2t, u0.w), w[3], d0);
        d0 = fdot2f(__builtin_bit_cast(half2t, u1.x), w[4], d0);
        d0 = fdot2f(__builtin_bit_cast(half2t, u1.y), w[5], d0);
        d0 = fdot2f(__builtin_bit_cast(half2t, u1.z), w[6], d0);
        d0 = fdot2f(__builtin_bit_cast(half2t, u1.w), w[7], d0);
        d1 = fdot2f(__builtin_bit_cast(half2t, u2.x), w[0], d1);
        d1 = fdot2f(__builtin_bit_cast(half2t, u2.y), w[1], d1);
        d1 = fdot2f(__builtin_bit_cast(half2t, u2.z), w[2], d1);
        d1 = fdot2f(__builtin_bit_cast(half2t, u2.w), w[3], d1);
        d1 = fdot2f(__builtin_bit_cast(half2t, u3.x), w[4], d1);
        d1 = fdot2f(__builtin_bit_cast(half2t, u3.y), w[5], d1);
        d1 = fdot2f(__builtin_bit_cast(half2t, u3.z), w[6], d1);
        d1 = fdot2f(__builtin_bit_cast(half2t, u3.w), w[7], d1);
        r0 += wt * d0;
        r1 += wt * d1;
    }

    half2t o; o.x = (_Float16)r0; o.y = (_Float16)r1;
    *(half2t*)(outp + ((size_t)b * 4096 + p) * 256 + cb) = o;
}

// D5: final GEMM (f16 A, f32 out)
__global__ __launch_bounds__(256) void gemm_final(
    const _Float16* __restrict__ A, const _Float16* __restrict__ Wmt,
    const float* __restrict__ bias, float* __restrict__ C)
{
    __shared__ _Float16 As[128 * LDT];
    __shared__ _Float16 Bs[128 * LDT];
    const int m0 = blockIdx.y * 128, n0 = blockIdx.x * 128;
    f32x4 acc[4][4] = {};
    gemm_core<_Float16>(As, Bs, A, Wmt, m0, n0, acc);
    const int t = threadIdx.x, lane = t & 63, wid = t >> 6;
    const int wr = wid >> 1, wc = wid & 1, lr = lane & 15;
    #pragma unroll
    for (int n = 0; n < 4; ++n) {
        const int col = n0 + wc*64 + n*16 + lr;
        const float bv = bias[col];
        #pragma unroll
        for (int m = 0; m < 4; ++m)
            #pragma unroll
            for (int r = 0; r < 4; ++r) {
                const int row = m0 + wr*64 + m*16 + (lane >> 4)*4 + r;
                C[(size_t)row * 256 + col] = acc[m][n][r] + bv;
            }
    }
}

extern "C" void kernel_launch(void* const* d_in, const int* in_sizes, int n_in,
                              void* d_out, int out_size, void* d_ws, size_t ws_size,
                              hipStream_t stream)
{
    const float* q   = (const float*)d_in[0];
    const float* ref = (const float*)d_in[1];
    const float* f0  = (const float*)d_in[2];
    const float* f1  = (const float*)d_in[3];
    const float* f2  = (const float*)d_in[4];
    const float* f3  = (const float*)d_in[5];
    const float* Wz  = (const float*)d_in[6];
    const float* bz  = (const float*)d_in[7];
    const float* Wo  = (const float*)d_in[8];
    const float* bo  = (const float*)d_in[9];
    const float* Wa  = (const float*)d_in[10];
    const float* ba  = (const float*)d_in[11];
    const float* Wp  = (const float*)d_in[12];
    const float* bp  = (const float*)d_in[13];
    const float* Wm  = (const float*)d_in[14];
    const float* bm  = (const float*)d_in[15];
    float* out = (float*)d_out;

    char* ws = (char*)d_ws;
    _Float16* z    = (_Float16*)(ws + ((size_t)0));          // f16 8MB
    _Float16* zo   = (_Float16*)(ws + ((size_t)16 << 20));   // f16 8MB
    _Float16* attn = (_Float16*)(ws + ((size_t)24 << 20));   // f16 4MB
    _Float16* wp0  = (_Float16*)(ws + ((size_t)28 << 20));   // f16 8MB
    _Float16* wp1  = (_Float16*)(ws + ((size_t)36 << 20));   // f16 2MB
    _Float16* wp2  = (_Float16*)(ws + ((size_t)38 << 20));   // f16 0.5MB
    _Float16* wp3  = (_Float16*)(ws + ((size_t)38 << 20) + ((size_t)512 << 10)); // 0.125MB
    _Float16* Wzt  = (_Float16*)(ws + ((size_t)40 << 20));                       // 128KB
    _Float16* Woat = (_Float16*)(ws + ((size_t)40 << 20) + ((size_t)256 << 10)); // 192KB
    _Float16* Wpt  = (_Float16*)(ws + ((size_t)40 << 20) + ((size_t)768 << 10)); // 128KB
    _Float16* Wmt  = (_Float16*)(ws + ((size_t)41 << 20));                       // 128KB
    _Float16* outp = z;  // f16 8MB, z dead after D2

    const dim3 blk(256);

    // D0: weights -> f16 transposed
    transpose_w<<<dim3(72), blk, 0, stream>>>(Wz, Wo, Wa, Wp, Wm, Wzt, Woat, Wpt, Wmt);
    // D1: z = f16(q@Wz+bz) AND wp_l = f16(feat_l@Wp+bp) (plane layout)
    gemm_z_wp<<<dim3(2, 298), blk, 0, stream>>>(q, Wzt, bz, z,
                                                f0, f1, f2, f3, Wpt, bp,
                                                wp0, wp1, wp2, wp3);
    // D2: zo (permuted channels) AND attn (fused LDS softmax)
    gemm_zo_at<<<dim3(3, 128), blk, 0, stream>>>(z, Woat, bo, ba, zo, attn);
    // D4: sampling -> out_pre f16 (overwrites z region)
    sample8<<<dim3(8192), blk, 0, stream>>>(zo, attn, ref, wp0, wp1, wp2, wp3, outp);
    // D5: out = out_pre@Wm+bm
    gemm_final<<<dim3(2, 128), blk, 0, stream>>>(outp, Wmt, bm, out);
}

// Round 13
// 90.188 us; speedup vs baseline: 1.1295x; 1.0507x over previous
//
#include <hip/hip_runtime.h>
#include <hip/hip_bf16.h>

// DeformableAttention: BS=4, Hq=Wq=64, C=256, M=8, K=4, L=4, CV=32
// SCALES = 64,32,16,8
//
// All-f16 pipeline, pre-transposed f16 weights, locality-optimized layouts:
//  D0 transpose_w: Wz,Wo,Wa,Wp,Wm (f32 [k][n]) -> f16 [n][k]
//  D1 gemm_z_wp : z = f16(q@Wz+bz)  AND  wp_l = f16(feat_l@Wp+bp)
//                 wp stored as per-(b,m) planes [(b*8+m)][hw*hw][32]
//  D2 gemm_zo_at: zo = f16(z@Wo+bo) with offset-channel permutation, AND
//                 za blocks: LDS-transpose + register-local softmax -> attn
//  D4 sample8   : wave=level, cluster=k, 32ch/lane via fdot2
//  D5 gemm_final: out = out_pre@Wm+bm -> f32
//
// GEMM staging (this round): LDS tiles linear [128][32] f16 with 16B-quarter
// XOR swizzle phys_q = sem_q ^ (row&3); f16 operands staged via
// __builtin_amdgcn_global_load_lds width=16 (pre-swizzled global source,
// linear LDS dest); f32 A reg-staged into the same swizzled layout.
//
// ws (MB): z/out_pre@0(8) zo@16(8) attn@24(4)
//   wp0@28(8) wp1@36(2) wp2@38(.5) wp3@38.5(.125)
//   Wzt@40 Woat@40.25 Wpt@40.75 Wmt@41. Peak ~41.25 MB.

typedef __attribute__((ext_vector_type(8))) _Float16 half8;
typedef __attribute__((ext_vector_type(2))) _Float16 half2t;
typedef __attribute__((ext_vector_type(4))) float f32x4;

#if __has_builtin(__builtin_amdgcn_fdot2)
__device__ __forceinline__ float fdot2f(half2t a, half2t b, float c) {
    return __builtin_amdgcn_fdot2(a, b, c, false);
}
#else
__device__ __forceinline__ float fdot2f(half2t a, half2t b, float c) {
    return c + (float)a.x * (float)b.x + (float)a.y * (float)b.y;
}
#endif

#define GLOAD_LDS16(gp, lp)                                                      \
    __builtin_amdgcn_global_load_lds(                                            \
        (const __attribute__((address_space(1))) void*)(gp),                     \
        (__attribute__((address_space(3))) void*)(lp), 16, 0, 0)

// f16-element offset of (row, semantic 8-elem quarter) in a [128][32] tile
__device__ __forceinline__ int swz(int row, int sem_q) {
    return row * 32 + ((sem_q ^ (row & 3)) * 8);
}

// ---------------------------------------------------------------------------
// D0: transpose+convert weights. 64x64 tiles via LDS. 72 blocks.
// ---------------------------------------------------------------------------
__global__ __launch_bounds__(256) void transpose_w(
    const float* __restrict__ Wz, const float* __restrict__ Wo,
    const float* __restrict__ Wa, const float* __restrict__ Wp,
    const float* __restrict__ Wm,
    _Float16* __restrict__ Wzt, _Float16* __restrict__ Woat,
    _Float16* __restrict__ Wpt, _Float16* __restrict__ Wmt)
{
    __shared__ float ts[64][65];
    const int bid = blockIdx.x;
    const float* src; _Float16* dst; int N, tile;
    if      (bid < 16) { src = Wz; dst = Wzt;          N = 256; tile = bid; }
    else if (bid < 32) { src = Wo; dst = Woat;         N = 256; tile = bid - 16; }
    else if (bid < 40) { src = Wa; dst = Woat + 65536; N = 128; tile = bid - 32; }
    else if (bid < 56) { src = Wp; dst = Wpt;          N = 256; tile = bid - 40; }
    else               { src = Wm; dst = Wmt;          N = 256; tile = bid - 56; }
    const int ntn = N >> 6;
    const int k0 = (tile / ntn) * 64, n0 = (tile % ntn) * 64;
    const int t = threadIdx.x, tx = t & 63, ty = t >> 6;
    #pragma unroll
    for (int r = 0; r < 16; ++r) {
        const int kk = r * 4 + ty;
        ts[kk][tx] = src[(size_t)(k0 + kk) * N + n0 + tx];
    }
    __syncthreads();
    #pragma unroll
    for (int r = 0; r < 16; ++r) {
        const int nn = r * 4 + ty;
        dst[(size_t)(n0 + nn) * 256 + k0 + tx] = (_Float16)ts[tx][nn];
    }
}

// ---------------------------------------------------------------------------
// GEMM core: acc[4][4] += A[128 rows at m0][256] @ Bt[128 rows at n0][256]^T
// As/Bs are [128][32] f16, quarter-swizzled. B staged via global_load_lds;
// A via global_load_lds when f16, reg-staged+converted when f32.
// ---------------------------------------------------------------------------
template<typename AT>
__device__ __forceinline__ void gemm_core(
    _Float16* __restrict__ As, _Float16* __restrict__ Bs,
    const AT* __restrict__ A, const _Float16* __restrict__ Bt,
    int m0, int n0, f32x4 (&acc)[4][4])
{
    const int t    = threadIdx.x;
    const int lane = t & 63, wid = t >> 6;
    const int wr = wid >> 1, wc = wid & 1;
    const int lr = lane & 15, sq = lane >> 4;

    // gload geometry: per wave, 2 instrs/operand; lane covers (row, phys q)
    const int grow = lane >> 2;                       // 0..15 within group
    const int gqs  = (lane & 3) ^ ((lane >> 2) & 3);  // semantic quarter to fetch

    for (int kt = 0; kt < 256; kt += 32) {
        if constexpr (sizeof(AT) == 4) {
            // reg-stage f32 -> f16 into swizzled layout
            const int arow = t >> 1, ac = t & 1;
            const float* ap = (const float*)A + (size_t)(m0 + arow) * 256 + kt + ac * 16;
            float v[16];
            #pragma unroll
            for (int i = 0; i < 4; ++i) {
                float4 f = ((const float4*)ap)[i];
                v[4*i] = f.x; v[4*i+1] = f.y; v[4*i+2] = f.z; v[4*i+3] = f.w;
            }
            half8 h0, h1;
            #pragma unroll
            for (int i = 0; i < 8; ++i) { h0[i] = (_Float16)v[i]; h1[i] = (_Float16)v[8+i]; }
            *(half8*)&As[swz(arow, ac * 2)]     = h0;
            *(half8*)&As[swz(arow, ac * 2 + 1)] = h1;
        } else {
            #pragma unroll
            for (int h = 0; h < 2; ++h) {
                const int rbase = wid * 32 + h * 16;
                const _Float16* ga = (const _Float16*)A +
                    (size_t)(m0 + rbase + grow) * 256 + kt + gqs * 8;
                GLOAD_LDS16(ga, &As[rbase * 32]);
            }
        }
        #pragma unroll
        for (int h = 0; h < 2; ++h) {
            const int rbase = wid * 32 + h * 16;
            const _Float16* gb = Bt +
                (size_t)(n0 + rbase + grow) * 256 + kt + gqs * 8;
            GLOAD_LDS16(gb, &Bs[rbase * 32]);
        }
        __syncthreads();

        half8 af[4], bf[4];
        #pragma unroll
        for (int m = 0; m < 4; ++m)
            af[m] = *(const half8*)&As[swz(wr*64 + m*16 + lr, sq)];
        #pragma unroll
        for (int n = 0; n < 4; ++n)
            bf[n] = *(const half8*)&Bs[swz(wc*64 + n*16 + lr, sq)];
        #pragma unroll
        for (int m = 0; m < 4; ++m)
            #pragma unroll
            for (int n = 0; n < 4; ++n)
                acc[m][n] = __builtin_amdgcn_mfma_f32_16x16x32_f16(af[m], bf[n], acc[m][n], 0, 0, 0);
        __syncthreads();
    }
}

// f16 store epilogue (row-major [rows][N])
__device__ __forceinline__ void epi_f16(
    f32x4 (&acc)[4][4], const float* __restrict__ bias,
    _Float16* __restrict__ C, int N, int m0, int n0)
{
    const int t = threadIdx.x, lane = t & 63, wid = t >> 6;
    const int wr = wid >> 1, wc = wid & 1, lr = lane & 15;
    #pragma unroll
    for (int n = 0; n < 4; ++n) {
        const int col = n0 + wc*64 + n*16 + lr;
        const float bv = bias[col];
        #pragma unroll
        for (int m = 0; m < 4; ++m)
            #pragma unroll
            for (int r = 0; r < 4; ++r) {
                const int row = m0 + wr*64 + m*16 + (lane >> 4)*4 + r;
                C[(size_t)row * N + col] = (_Float16)(acc[m][n][r] + bv);
            }
    }
}

// wp store epilogue: plane layout C[((b*8+mh)<<shift) + pix][32]
__device__ __forceinline__ void epi_wp(
    f32x4 (&acc)[4][4], const float* __restrict__ bias,
    _Float16* __restrict__ C, int m0, int n0, int shift)
{
    const int t = threadIdx.x, lane = t & 63, wid = t >> 6;
    const int wr = wid >> 1, wc = wid & 1, lr = lane & 15;
    const int mask = (1 << shift) - 1;
    #pragma unroll
    for (int n = 0; n < 4; ++n) {
        const int col = n0 + wc*64 + n*16 + lr;
        const float bv = bias[col];
        const int mh = col >> 5, cv = col & 31;
        #pragma unroll
        for (int m = 0; m < 4; ++m)
            #pragma unroll
            for (int r = 0; r < 4; ++r) {
                const int row = m0 + wr*64 + m*16 + (lane >> 4)*4 + r;
                const int bb = row >> shift, pix = row & mask;
                C[((((size_t)(bb * 8 + mh)) << shift) + pix) * 32 + cv] =
                    (_Float16)(acc[m][n][r] + bv);
            }
    }
}

// D1: z GEMM (by<128) + all 4 wp GEMMs (by>=128, plane-layout stores)
__global__ __launch_bounds__(256) void gemm_z_wp(
    const float* __restrict__ q, const _Float16* __restrict__ Wzt,
    const float* __restrict__ bz, _Float16* __restrict__ z,
    const float* __restrict__ f0, const float* __restrict__ f1,
    const float* __restrict__ f2, const float* __restrict__ f3,
    const _Float16* __restrict__ Wpt, const float* __restrict__ bp,
    _Float16* __restrict__ w0, _Float16* __restrict__ w1,
    _Float16* __restrict__ w2, _Float16* __restrict__ w3)
{
    __shared__ _Float16 As[128 * 32];
    __shared__ _Float16 Bs[128 * 32];
    const int by = blockIdx.y, bx = blockIdx.x;
    f32x4 acc[4][4] = {};
    if (by < 128) {
        gemm_core<float>(As, Bs, q, Wzt, by * 128, bx * 128, acc);
        epi_f16(acc, bz, z, 256, by * 128, bx * 128);
    } else {
        const int y = by - 128;
        const float* A; _Float16* C; int m0, shift;
        if      (y < 128) { A = f0; C = w0; m0 = y * 128;         shift = 12; }
        else if (y < 160) { A = f1; C = w1; m0 = (y - 128) * 128; shift = 10; }
        else if (y < 168) { A = f2; C = w2; m0 = (y - 160) * 128; shift = 8;  }
        else              { A = f3; C = w3; m0 = (y - 168) * 128; shift = 6;  }
        gemm_core<float>(As, Bs, A, Wpt, m0, bx * 128, acc);
        epi_wp(acc, bp, C, m0, bx * 128, shift);
    }
}

// D2: zo GEMM with channel permutation (bx<2) + za GEMM with fused
// LDS-transpose softmax (bx==2). smax[128][136] overlaid on As/Bs.
__global__ __launch_bounds__(256) void gemm_zo_at(
    const _Float16* __restrict__ z, const _Float16* __restrict__ Woat,
    const float* __restrict__ bo, const float* __restrict__ ba,
    _Float16* __restrict__ zo, _Float16* __restrict__ attn)
{
    __shared__ __align__(16) char ldsbuf[128 * 136 * 2];  // 34816B
    _Float16* As = (_Float16*)ldsbuf;
    _Float16* Bs = As + 128 * 32;
    _Float16 (*smax)[136] = (_Float16(*)[136])ldsbuf;

    const int bx = blockIdx.x, by = blockIdx.y;
    const int m0 = by * 128;
    f32x4 acc[4][4] = {};
    gemm_core<_Float16>(As, Bs, z, Woat, m0, bx * 128, acc);

    const int t = threadIdx.x, lane = t & 63, wid = t >> 6;
    const int wr = wid >> 1, wc = wid & 1, lr = lane & 15;

    if (bx < 2) {
        #pragma unroll
        for (int n = 0; n < 4; ++n) {
            const int c = bx * 128 + wc*64 + n*16 + lr;
            const float bv = bo[c];
            const int cp = (((c >> 3) & 3) << 6) | ((c >> 5) << 3)
                         | (((c >> 1) & 3) << 1) | (c & 1);
            #pragma unroll
            for (int m = 0; m < 4; ++m)
                #pragma unroll
                for (int r = 0; r < 4; ++r) {
                    const int row = m0 + wr*64 + m*16 + (lane >> 4)*4 + r;
                    zo[(size_t)row * 256 + cp] = (_Float16)(acc[m][n][r] + bv);
                }
        }
    } else {
        __syncthreads();  // ensure all waves done with As/Bs before overlay
        #pragma unroll
        for (int n = 0; n < 4; ++n) {
            const int col = wc*64 + n*16 + lr;
            const float bv = ba[col];
            #pragma unroll
            for (int m = 0; m < 4; ++m)
                #pragma unroll
                for (int r = 0; r < 4; ++r) {
                    const int rowl = wr*64 + m*16 + (lane >> 4)*4 + r;
                    smax[rowl][col] = (_Float16)(acc[m][n][r] + bv);
                }
        }
        __syncthreads();
        #pragma unroll
        for (int j = 0; j < 4; ++j) {
            const int g    = j * 256 + t;
            const int rowl = g >> 3, mh = g & 7;
            const half8* sp = (const half8*)&smax[rowl][mh * 16];
            const half8 a = sp[0], bb8 = sp[1];
            float v[16];
            #pragma unroll
            for (int i = 0; i < 8; ++i) { v[i] = (float)a[i]; v[8+i] = (float)bb8[i]; }
            float mx = v[0];
            #pragma unroll
            for (int i = 1; i < 16; ++i) mx = fmaxf(mx, v[i]);
            float s = 0.f;
            #pragma unroll
            for (int i = 0; i < 16; ++i) { v[i] = expf(v[i] - mx); s += v[i]; }
            const float inv = 1.f / s;
            half8 o0, o1;
            #pragma unroll
            for (int i = 0; i < 8; ++i) { o0[i] = (_Float16)(v[i]*inv); o1[i] = (_Float16)(v[8+i]*inv); }
            const int row  = m0 + rowl;
            const int qpos = row & 4095, b = row >> 12;
            const int k = qpos >> 10, qx = (qpos >> 4) & 63, ya = qpos & 15;
            half8* op = (half8*)(attn +
                ((((((size_t)b * 64 + qx) * 16 + ya) * 8 + mh) * 4 + k) * 16));
            op[0] = o0; op[1] = o1;
        }
    }
}

// D4: sample8. Block = 2 queries (XCD-swizzled); t = l*64 + qp*32 + m*4 + k.
__global__ __launch_bounds__(256) void sample8(
    const _Float16* __restrict__ zo,    // f16 [b][qy][qx][perm 256]
    const _Float16* __restrict__ attn,  // f16 [b][qx][ya][m][k][16]
    const float* __restrict__ ref,      // f32 [BS][64][64][2]
    const _Float16* __restrict__ wp0, const _Float16* __restrict__ wp1,
    const _Float16* __restrict__ wp2, const _Float16* __restrict__ wp3,
    _Float16* __restrict__ outp)        // f16 [b][p][256]
{
    const int bid = blockIdx.x;
    const int bp_ = (bid & 7) * 1024 + (bid >> 3);
    const int t  = threadIdx.x;
    const int k  = t & 3;
    const int m  = (t >> 2) & 7;
    const int qp = (t >> 5) & 1;
    const int l  = t >> 6;

    const int query = bp_ * 2 + qp;
    const int qx = query & 63;
    const int qy = (query >> 6) & 63;
    const int b  = query >> 12;

    const int ya = qy >> 2, yb = qy & 3;
    const int p  = (k << 10) | (qx << 4) | ya;
    const int cb = m * 32 + yb * 8 + l * 2;

    const int hw = 64 >> l;
    const int shift = 12 - 2 * l;
    const float fw = (float)hw;
    const _Float16* wp = (l == 0) ? wp0 : (l == 1) ? wp1 : (l == 2) ? wp2 : wp3;

    const unsigned off2 = *(const unsigned*)(zo + (size_t)query * 256 + (l * 64 + m * 8 + k * 2));
    const half2t offh = __builtin_bit_cast(half2t, off2);
    const float offx = (float)offh.x;
    const float offy = (float)offh.y;

    const int rb = m & 3;
    const float2 rr = *(const float2*)(ref + ((size_t)(rb * 4096) + qy * 64 + qx) * 2);

    const float px  = rr.x * (fw - 1.f) + offx;
    const float py  = rr.y * (fw - 1.f) + offy;
    const float gx  = 2.f * px / (fw - 1.f) - 1.f;
    const float gy  = 2.f * py / (fw - 1.f) - 1.f;
    const float xim = (gx + 1.f) * (fw * 0.5f) - 0.5f;
    const float yim = (gy + 1.f) * (fw * 0.5f) - 0.5f;

    const float x0f = floorf(xim), y0f = floorf(yim);
    const float wx1 = xim - x0f, wy1 = yim - y0f;
    const float wx0 = 1.f - wx1, wy0 = 1.f - wy1;
    const int ix0 = (int)x0f, iy0 = (int)y0f;

    half2t w[8];
    {
        const uint4* ap = (const uint4*)(attn +
            ((((((size_t)b * 64 + qx) * 16 + ya) * 8 + m) * 4 + k) * 16));
        const uint4 wa = ap[0], wb = ap[1];
        w[0] = __builtin_bit_cast(half2t, wa.x); w[1] = __builtin_bit_cast(half2t, wa.y);
        w[2] = __builtin_bit_cast(half2t, wa.z); w[3] = __builtin_bit_cast(half2t, wa.w);
        w[4] = __builtin_bit_cast(half2t, wb.x); w[5] = __builtin_bit_cast(half2t, wb.y);
        w[6] = __builtin_bit_cast(half2t, wb.z); w[7] = __builtin_bit_cast(half2t, wb.w);
    }

    const _Float16* plane = wp + ((((size_t)(b * 8 + m)) << shift) * 32);

    float r0 = 0.f, r1 = 0.f;
    #pragma unroll
    for (int tap = 0; tap < 4; ++tap) {
        int iy = iy0 + (tap >> 1);
        int ix = ix0 + (tap & 1);
        const bool ok = (iy >= 0) & (iy < hw) & (ix >= 0) & (ix < hw);
        float wt = ((tap >> 1) ? wy1 : wy0) * ((tap & 1) ? wx1 : wx0);
        wt = ok ? wt : 0.f;
        iy = min(max(iy, 0), hw - 1);
        ix = min(max(ix, 0), hw - 1);
        const uint4* tp = (const uint4*)(plane + ((size_t)(iy * hw + ix)) * 32);
        const uint4 u0 = tp[0], u1 = tp[1], u2 = tp[2], u3 = tp[3];
        float d0 = 0.f, d1 = 0.f;
        d0 = fdot2f(__builtin_bit_cast(half2t, u0.x), w[0], d0);
        d0 = fdot2f(__builtin_bit_cast(half2t, u0.y), w[1], d0);
        d0 = fdot2f(__builtin_bit_cast(half2t, u0.z), w[2], d0);
        d0 = fdot2f(__builtin_bit_cast(half2t, u0.w), w[3], d0);
        d0 = fdot2f(__builtin_bit_cast(half2t, u1.x), w[4], d0);
        d0 = fdot2f(__builtin_bit_cast(half2t, u1.y), w[5], d0);
        d0 = fdot2f(__builtin_bit_cast(half2t, u1.z), w[6], d0);
        d0 = fdot2f(__builtin_bit_cast(half2t, u1.w), w[7], d0);
        d1 = fdot2f(__builtin_bit_cast(half2t, u2.x), w[0], d1);
        d1 = fdot2f(__builtin_bit_cast(half2t, u2.y), w[1], d1);
        d1 = fdot2f(__builtin_bit_cast(half2t, u2.z), w[2], d1);
        d1 = fdot2f(__builtin_bit_cast(half2t, u2.w), w[3], d1);
        d1 = fdot2f(__builtin_bit_cast(half2t, u3.x), w[4], d1);
        d1 = fdot2f(__builtin_bit_cast(half2t, u3.y), w[5], d1);
        d1 = fdot2f(__builtin_bit_cast(half2t, u3.z), w[6], d1);
        d1 = fdot2f(__builtin_bit_cast(half2t, u3.w), w[7], d1);
        r0 += wt * d0;
        r1 += wt * d1;
    }

    half2t o; o.x = (_Float16)r0; o.y = (_Float16)r1;
    *(half2t*)(outp + ((size_t)b * 4096 + p) * 256 + cb) = o;
}

// D5: final GEMM (f16 A, f32 out)
__global__ __launch_bounds__(256) void gemm_final(
    const _Float16* __restrict__ A, const _Float16* __restrict__ Wmt,
    const float* __restrict__ bias, float* __restrict__ C)
{
    __shared__ _Float16 As[128 * 32];
    __shared__ _Float16 Bs[128 * 32];
    const int m0 = blockIdx.y * 128, n0 = blockIdx.x * 128;
    f32x4 acc[4][4] = {};
    gemm_core<_Float16>(As, Bs, A, Wmt, m0, n0, acc);
    const int t = threadIdx.x, lane = t & 63, wid = t >> 6;
    const int wr = wid >> 1, wc = wid & 1, lr = lane & 15;
    #pragma unroll
    for (int n = 0; n < 4; ++n) {
        const int col = n0 + wc*64 + n*16 + lr;
        const float bv = bias[col];
        #pragma unroll
        for (int m = 0; m < 4; ++m)
            #pragma unroll
            for (int r = 0; r < 4; ++r) {
                const int row = m0 + wr*64 + m*16 + (lane >> 4)*4 + r;
                C[(size_t)row * 256 + col] = acc[m][n][r] + bv;
            }
    }
}

extern "C" void kernel_launch(void* const* d_in, const int* in_sizes, int n_in,
                              void* d_out, int out_size, void* d_ws, size_t ws_size,
                              hipStream_t stream)
{
    const float* q   = (const float*)d_in[0];
    const float* ref = (const float*)d_in[1];
    const float* f0  = (const float*)d_in[2];
    const float* f1  = (const float*)d_in[3];
    const float* f2  = (const float*)d_in[4];
    const float* f3  = (const float*)d_in[5];
    const float* Wz  = (const float*)d_in[6];
    const float* bz  = (const float*)d_in[7];
    const float* Wo  = (const float*)d_in[8];
    const float* bo  = (const float*)d_in[9];
    const float* Wa  = (const float*)d_in[10];
    const float* ba  = (const float*)d_in[11];
    const float* Wp  = (const float*)d_in[12];
    const float* bp  = (const float*)d_in[13];
    const float* Wm  = (const float*)d_in[14];
    const float* bm  = (const float*)d_in[15];
    float* out = (float*)d_out;

    char* ws = (char*)d_ws;
    _Float16* z    = (_Float16*)(ws + ((size_t)0));          // f16 8MB
    _Float16* zo   = (_Float16*)(ws + ((size_t)16 << 20));   // f16 8MB
    _Float16* attn = (_Float16*)(ws + ((size_t)24 << 20));   // f16 4MB
    _Float16* wp0  = (_Float16*)(ws + ((size_t)28 << 20));   // f16 8MB
    _Float16* wp1  = (_Float16*)(ws + ((size_t)36 << 20));   // f16 2MB
    _Float16* wp2  = (_Float16*)(ws + ((size_t)38 << 20));   // f16 0.5MB
    _Float16* wp3  = (_Float16*)(ws + ((size_t)38 << 20) + ((size_t)512 << 10)); // 0.125MB
    _Float16* Wzt  = (_Float16*)(ws + ((size_t)40 << 20));                       // 128KB
    _Float16* Woat = (_Float16*)(ws + ((size_t)40 << 20) + ((size_t)256 << 10)); // 192KB
    _Float16* Wpt  = (_Float16*)(ws + ((size_t)40 << 20) + ((size_t)768 << 10)); // 128KB
    _Float16* Wmt  = (_Float16*)(ws + ((size_t)41 << 20));                       // 128KB
    _Float16* outp = z;  // f16 8MB, z dead after D2

    const dim3 blk(256);

    // D0: weights -> f16 transposed
    transpose_w<<<dim3(72), blk, 0, stream>>>(Wz, Wo, Wa, Wp, Wm, Wzt, Woat, Wpt, Wmt);
    // D1: z = f16(q@Wz+bz) AND wp_l = f16(feat_l@Wp+bp) (plane layout)
    gemm_z_wp<<<dim3(2, 298), blk, 0, stream>>>(q, Wzt, bz, z,
                                                f0, f1, f2, f3, Wpt, bp,
                                                wp0, wp1, wp2, wp3);
    // D2: zo (permuted channels) AND attn (fused LDS softmax)
    gemm_zo_at<<<dim3(3, 128), blk, 0, stream>>>(z, Woat, bo, ba, zo, attn);
    // D4: sampling -> out_pre f16 (overwrites z region)
    sample8<<<dim3(8192), blk, 0, stream>>>(zo, attn, ref, wp0, wp1, wp2, wp3, outp);
    // D5: out = out_pre@Wm+bm
    gemm_final<<<dim3(2, 128), blk, 0, stream>>>(outp, Wmt, bm, out);
}